// Round 3
// baseline (99.081 us; speedup 1.0000x reference)
//
#include <hip/hip_runtime.h>
#include <math.h>

#define SCALE 8
#define PSZ 32

// ---- constant twiddles: W_32^k = cos(2pi k/32) - i sin(2pi k/32), k=0..15 ----
__device__ constexpr float C32[16] = {
     1.000000000000000f,  0.980785280403230f,  0.923879532511287f,  0.831469612302545f,
     0.707106781186548f,  0.555570233019602f,  0.382683432365090f,  0.195090322016128f,
     0.000000000000000f, -0.195090322016128f, -0.382683432365090f, -0.555570233019602f,
    -0.707106781186548f, -0.831469612302545f, -0.923879532511287f, -0.980785280403230f };
__device__ constexpr float S32[16] = {
     0.000000000000000f,  0.195090322016128f,  0.382683432365090f,  0.555570233019602f,
     0.707106781186548f,  0.831469612302545f,  0.923879532511287f,  0.980785280403230f,
     1.000000000000000f,  0.980785280403230f,  0.923879532511287f,  0.831469612302545f,
     0.707106781186548f,  0.555570233019602f,  0.382683432365090f,  0.195090322016128f };

__device__ __forceinline__ constexpr int brev5(int i) {
    return ((i & 1) << 4) | ((i & 2) << 2) | (i & 4) | ((i & 8) >> 2) | ((i & 16) >> 4);
}

// in-place 32-point radix-2 DIT FFT, fully unrolled (all indices compile-time,
// trivial twiddles constant-folded by the compiler)
__device__ __forceinline__ void fft32(float re[PSZ], float im[PSZ]) {
#pragma unroll
    for (int i = 0; i < 32; ++i) {
        const int j = brev5(i);
        if (j > i) {
            float t = re[i]; re[i] = re[j]; re[j] = t;
            t = im[i]; im[i] = im[j]; im[j] = t;
        }
    }
#pragma unroll
    for (int s = 1; s <= 5; ++s) {
        const int m = 1 << s;
        const int h = m >> 1;
        const int tstep = 32 >> s;
#pragma unroll
        for (int k = 0; k < 32; k += m) {
#pragma unroll
            for (int j = 0; j < h; ++j) {
                const float wr = C32[j * tstep];
                const float wi = -S32[j * tstep];
                const int a = k + j;
                const int b = k + j + h;
                const float tr = wr * re[b] - wi * im[b];
                const float ti = wr * im[b] + wi * re[b];
                re[b] = re[a] - tr; im[b] = im[a] - ti;
                re[a] = re[a] + tr; im[a] = im[a] + ti;
            }
        }
    }
}

// bf16x2 pack/unpack (round-half-up via +0x8000)
__device__ __forceinline__ unsigned pack_bf2(float hi, float lo) {
    const unsigned uh = __float_as_uint(hi) + 0x8000u;
    const unsigned ul = __float_as_uint(lo) + 0x8000u;
    return (uh & 0xFFFF0000u) | (ul >> 16);
}
__device__ __forceinline__ float bf_hi(unsigned u) { return __uint_as_float(u & 0xFFFF0000u); }
__device__ __forceinline__ float bf_lo(unsigned u) { return __uint_as_float(u << 16); }

// 128-thread block = 2 waves; each wave independently handles 4 patches.
// Row stage (per wave): lane (g=lane>>5, r=lane&31) packs row r of patches
// (2g, 2g+1) as a + i*b -> ONE complex FFT32 -> unpack to the two real-row
// spectra (Hermitian: only k=0..16; k=0 & k=16 are real, packed into slot 0).
// Spectra stored in LDS as bf16x2 u32, XOR-swizzled layout
//   idx = slot*32 + (row ^ 2*slot)   (2048 B / patch, conflict-free)
// Col stage: lane (pl=lane>>4, slot=lane&15): 15 complex column FFTs + 1
// packed real-pair column FFT per patch; masked log-power sums with
// compile-time Hermitian mirror weights {0,1,2}; 16-lane shuffle reduce;
// global max via uint atomicMax (sums are >= 0).
__global__ __launch_bounds__(128) void hfdft_patch_kernel(
        const float* __restrict__ x, const float* __restrict__ w,
        float* __restrict__ out, unsigned* __restrict__ mx,
        int H, int W, int mat_h, int mat_w) {
    __shared__ unsigned cb[8 * 512];   // 8 patches * 512 u32 (bf16x2), 16 KB

    const int tid = threadIdx.x;
    const int wid = tid >> 6;          // wave within block
    const int lane = tid & 63;
    const int P0 = blockIdx.x * 8 + wid * 4;
    const int total = mat_h * mat_w;
    const float w0 = w[0], w1 = w[1], w2 = w[2];
    const long long HW = (long long)H * W;

    // ================= row stage =================
    {
        const int g = lane >> 5, r = lane & 31;
        int pA = P0 + 2 * g;
        if (pA > total - 1) pA = total - 1;
        int pB = pA + 1; if (pB > total - 1) pB = total - 1;
        const int phA = pA / mat_w, pwA = pA % mat_w;
        const int phB = pB / mat_w, pwB = pB % mat_w;
        const bool adj = (phA == phB) && (pwB == pwA + 1);

        float re[PSZ], im[PSZ];
        if (adj && ((W & 3) == 0)) {
            // shared 40-px window: patch B starts SCALE=8 px right of A
            const int base = (phA * SCALE + r) * W + pwA * SCALE;
            const float4* a4 = reinterpret_cast<const float4*>(x + base);
            const float4* b4 = reinterpret_cast<const float4*>(x + HW + base);
            const float4* c4 = reinterpret_cast<const float4*>(x + 2 * HW + base);
            float win[40];
#pragma unroll
            for (int q = 0; q < 10; ++q) {
                const float4 a = a4[q], b = b4[q], c = c4[q];
                win[4 * q + 0] = w0 * a.x + w1 * b.x + w2 * c.x;
                win[4 * q + 1] = w0 * a.y + w1 * b.y + w2 * c.y;
                win[4 * q + 2] = w0 * a.z + w1 * b.z + w2 * c.z;
                win[4 * q + 3] = w0 * a.w + w1 * b.w + w2 * c.w;
            }
#pragma unroll
            for (int i = 0; i < PSZ; ++i) { re[i] = win[i]; im[i] = win[i + 8]; }
        } else {
            const int baseA = (phA * SCALE + r) * W + pwA * SCALE;
            const int baseB = (phB * SCALE + r) * W + pwB * SCALE;
#pragma unroll
            for (int i = 0; i < PSZ; ++i) {
                re[i] = w0 * x[baseA + i] + w1 * x[HW + baseA + i] + w2 * x[2 * HW + baseA + i];
                im[i] = w0 * x[baseB + i] + w1 * x[HW + baseB + i] + w2 * x[2 * HW + baseB + i];
            }
        }

        fft32(re, im);   // FFT of rowA + i*rowB

        // unpack the two real-row spectra; store k=0..16 (slot0 = (F(0),F(16)))
        unsigned* cbA = cb + (wid * 4 + 2 * g) * 512;
        unsigned* cbB = cbA + 512;
        cbA[r] = pack_bf2(re[0], re[16]);          // slot 0: idx = r ^ 0
        cbB[r] = pack_bf2(im[0], im[16]);
#pragma unroll
        for (int k = 1; k <= 15; ++k) {
            const int m = 32 - k;
            const float far_ = 0.5f * (re[k] + re[m]);
            const float fai_ = 0.5f * (im[k] - im[m]);
            const float fbr_ = 0.5f * (im[k] + im[m]);
            const float fbi_ = 0.5f * (re[m] - re[k]);
            const int idx = (k << 5) + (r ^ (2 * k));
            cbA[idx] = pack_bf2(far_, fai_);
            cbB[idx] = pack_bf2(fbr_, fbi_);
        }
    }

    __syncthreads();

    // ================= column stage =================
    {
        const int pl = lane >> 4, slot = lane & 15;
        const int p = P0 + pl;
        const unsigned* cbp = cb + (wid * 4 + pl) * 512 + (slot << 5);
        const int s2 = 2 * slot;

        float cre[PSZ], cim[PSZ];
#pragma unroll
        for (int r2 = 0; r2 < PSZ; ++r2) {
            const unsigned u = cbp[r2 ^ s2];
            cre[r2] = bf_hi(u);
            cim[r2] = bf_lo(u);
        }

        fft32(cre, cim);

        float s0 = 0.0f, s1 = 0.0f;
        if (slot == 0) {
            // packed pair (col 0, col 16): unpack kr=0..16, Hermitian-in-kr weights
#pragma unroll
            for (int kr = 0; kr <= 16; ++kr) {
                const int m = (32 - kr) & 31;
                const float g0r = 0.5f * (cre[kr] + cre[m]);
                const float g0i = 0.5f * (cim[kr] - cim[m]);
                const float g1r = 0.5f * (cim[kr] + cim[m]);
                const float g1i = 0.5f * (cre[m] - cre[kr]);
                const float w0c = (kr >= 7 ? 1.0f : 0.0f) + ((kr >= 8 && kr <= 15) ? 1.0f : 0.0f);
                const float w16c = 1.0f + ((kr >= 1 && kr <= 15) ? 1.0f : 0.0f);
                if (w0c > 0.0f)
                    s0 = fmaf(w0c, __logf(g0r * g0r + g0i * g0i + 1.0f), s0);
                s1 = fmaf(w16c, __logf(g1r * g1r + g1i * g1i + 1.0f), s1);
            }
        } else {
            // column kc=slot (1..15) + its mirror column 32-slot via weights
            const float b1f = (slot >= 7) ? 1.0f : 0.0f;   // base-column full
            const float m1f = (slot >= 8) ? 1.0f : 0.0f;   // mirror-column full
#pragma unroll
            for (int kr = 0; kr < 32; ++kr) {
                const float lp = __logf(cre[kr] * cre[kr] + cim[kr] * cim[kr] + 1.0f);
                float wgt;
                if (kr >= 8 && kr <= 24)      wgt = 2.0f;
                else if (kr == 7)             wgt = 1.0f + m1f;
                else if (kr == 25)            wgt = b1f + 1.0f;
                else                          wgt = b1f + m1f;
                if (kr & 1) s1 = fmaf(wgt, lp, s1);
                else        s0 = fmaf(wgt, lp, s0);
            }
        }
        float s = s0 + s1;

        // reduce across the 16 lanes of this patch
#pragma unroll
        for (int off = 8; off >= 1; off >>= 1) s += __shfl_xor(s, off, 16);
        if (slot == 0 && p < total) {
            out[p] = s;
            atomicMax(mx, __float_as_uint(s));   // s >= 0: uint order == float order
        }
    }
}

__global__ __launch_bounds__(256) void norm_kernel(
        float* __restrict__ out, int n, const unsigned* __restrict__ mx) {
    const int i = blockIdx.x * 256 + threadIdx.x;
    if (i < n) out[i] = out[i] / __uint_as_float(mx[0]);
}

extern "C" void kernel_launch(void* const* d_in, const int* in_sizes, int n_in,
                              void* d_out, int out_size, void* d_ws, size_t ws_size,
                              hipStream_t stream) {
    const float* x = (const float*)d_in[0];
    const float* w = (const float*)d_in[1];
    float* out = (float*)d_out;
    unsigned* maxbuf = (unsigned*)d_ws;

    const int HW = in_sizes[0] / 3;
    const int H = (int)(sqrt((double)HW) + 0.5);
    const int W = H;
    const int mat = (int)(sqrt((double)out_size) + 0.5);
    const int total = mat * mat;

    hipMemsetAsync(maxbuf, 0, 4, stream);   // async memset: graph-capture safe

    const int blocksA = (total + 7) / 8;
    hipLaunchKernelGGL(hfdft_patch_kernel, dim3(blocksA), dim3(128), 0, stream,
                       x, w, out, maxbuf, H, W, mat, mat);
    hipLaunchKernelGGL(norm_kernel, dim3((total + 255) / 256), dim3(256), 0, stream,
                       out, total, maxbuf);
}

// Round 4
// 43.845 us; speedup vs baseline: 2.2598x; 2.2598x over previous
//
#include <hip/hip_runtime.h>
#include <math.h>

#define SCALE 8
#define PSZ 32

// ---- constant twiddles: W_32^k = cos(2pi k/32) - i sin(2pi k/32), k=0..15 ----
__device__ constexpr float C32[16] = {
     1.000000000000000f,  0.980785280403230f,  0.923879532511287f,  0.831469612302545f,
     0.707106781186548f,  0.555570233019602f,  0.382683432365090f,  0.195090322016128f,
     0.000000000000000f, -0.195090322016128f, -0.382683432365090f, -0.555570233019602f,
    -0.707106781186548f, -0.831469612302545f, -0.923879532511287f, -0.980785280403230f };
__device__ constexpr float S32[16] = {
     0.000000000000000f,  0.195090322016128f,  0.382683432365090f,  0.555570233019602f,
     0.707106781186548f,  0.831469612302545f,  0.923879532511287f,  0.980785280403230f,
     1.000000000000000f,  0.980785280403230f,  0.923879532511287f,  0.831469612302545f,
     0.707106781186548f,  0.555570233019602f,  0.382683432365090f,  0.195090322016128f };

__device__ __forceinline__ constexpr int brev5(int i) {
    return ((i & 1) << 4) | ((i & 2) << 2) | (i & 4) | ((i & 8) >> 2) | ((i & 16) >> 4);
}

// in-place 32-point radix-2 DIT FFT, fully unrolled (all indices compile-time)
__device__ __forceinline__ void fft32(float re[PSZ], float im[PSZ]) {
#pragma unroll
    for (int i = 0; i < 32; ++i) {
        const int j = brev5(i);
        if (j > i) {
            float t = re[i]; re[i] = re[j]; re[j] = t;
            t = im[i]; im[i] = im[j]; im[j] = t;
        }
    }
#pragma unroll
    for (int s = 1; s <= 5; ++s) {
        const int m = 1 << s;
        const int h = m >> 1;
        const int tstep = 32 >> s;
#pragma unroll
        for (int k = 0; k < 32; k += m) {
#pragma unroll
            for (int j = 0; j < h; ++j) {
                const float wr = C32[j * tstep];
                const float wi = -S32[j * tstep];
                const int a = k + j;
                const int b = k + j + h;
                const float tr = wr * re[b] - wi * im[b];
                const float ti = wr * im[b] + wi * re[b];
                re[b] = re[a] - tr; im[b] = im[a] - ti;
                re[a] = re[a] + tr; im[a] = im[a] + ti;
            }
        }
    }
}

// bf16x2 pack/unpack (round-half-up via +0x8000)
__device__ __forceinline__ unsigned pack_bf2(float hi, float lo) {
    const unsigned uh = __float_as_uint(hi) + 0x8000u;
    const unsigned ul = __float_as_uint(lo) + 0x8000u;
    return (uh & 0xFFFF0000u) | (ul >> 16);
}
__device__ __forceinline__ float bf_hi(unsigned u) { return __uint_as_float(u & 0xFFFF0000u); }
__device__ __forceinline__ float bf_lo(unsigned u) { return __uint_as_float(u << 16); }

// ---- gray precompute: g = w0*R + w1*G + w2*B, vectorized float4 ----
__global__ __launch_bounds__(256) void gray_kernel(
        const float* __restrict__ x, const float* __restrict__ w,
        float* __restrict__ g, int n4, long long HW) {
    const int i = blockIdx.x * 256 + threadIdx.x;
    if (i >= n4) return;
    const float w0 = w[0], w1 = w[1], w2 = w[2];
    const float4 a = reinterpret_cast<const float4*>(x)[i];
    const float4 b = reinterpret_cast<const float4*>(x + HW)[i];
    const float4 c = reinterpret_cast<const float4*>(x + 2 * HW)[i];
    float4 o;
    o.x = w0 * a.x + w1 * b.x + w2 * c.x;
    o.y = w0 * a.y + w1 * b.y + w2 * c.y;
    o.z = w0 * a.z + w1 * b.z + w2 * c.z;
    o.w = w0 * a.w + w1 * b.w + w2 * c.w;
    reinterpret_cast<float4*>(g)[i] = o;
}

// One 64-thread block = 4 patches (R2-proven structure).
// Row stage: lane (g=lane>>5, r=lane&31) packs row r of patches (2g, 2g+1) as
// a + i*b -> ONE complex FFT32 -> unpack the two real-row spectra (Hermitian:
// k=0..16; k=0 & 16 real, packed into slot 0). LDS bf16x2, stride 33
// (2-way aliasing only = free).
// Col stage: lane (pl=lane>>4, slot=lane&15): 15 complex column FFTs + 1
// packed real-pair FFT per patch; masked log-power with Hermitian mirror
// weights {0,1,2}; 16-lane shuffle reduce.
template <bool GRAY_PRE>
__global__ __launch_bounds__(64) void hfdft_patch_kernel(
        const float* __restrict__ x, const float* __restrict__ w,
        float* __restrict__ out, int H, int W, int mat_h, int mat_w) {
    __shared__ unsigned cb[4 * 528];

    const int lane = threadIdx.x;
    const int total = mat_h * mat_w;
    const long long HW = (long long)H * W;

    // ================= row stage =================
    {
        const int g = lane >> 5, r = lane & 31;
        int pA = blockIdx.x * 4 + 2 * g;
        if (pA > total - 1) pA = total - 1;
        int pB = pA + 1; if (pB > total - 1) pB = total - 1;
        const int phA = pA / mat_w, pwA = pA % mat_w;
        const int phB = pB / mat_w, pwB = pB % mat_w;
        const bool adj = (phA == phB) && (pwB == pwA + 1);

        float re[PSZ], im[PSZ];
        if (GRAY_PRE) {
            if (adj) {
                const int base = (phA * SCALE + r) * W + pwA * SCALE;
                const float4* g4 = reinterpret_cast<const float4*>(x + base);
                float win[40];
#pragma unroll
                for (int q = 0; q < 10; ++q) {
                    const float4 v = g4[q];
                    win[4 * q + 0] = v.x; win[4 * q + 1] = v.y;
                    win[4 * q + 2] = v.z; win[4 * q + 3] = v.w;
                }
#pragma unroll
                for (int i = 0; i < PSZ; ++i) { re[i] = win[i]; im[i] = win[i + 8]; }
            } else {
                const int baseA = (phA * SCALE + r) * W + pwA * SCALE;
                const int baseB = (phB * SCALE + r) * W + pwB * SCALE;
#pragma unroll
                for (int i = 0; i < PSZ; ++i) { re[i] = x[baseA + i]; im[i] = x[baseB + i]; }
            }
        } else {
            const float w0 = w[0], w1 = w[1], w2 = w[2];
            if (adj && ((W & 3) == 0)) {
                const int base = (phA * SCALE + r) * W + pwA * SCALE;
                const float4* a4 = reinterpret_cast<const float4*>(x + base);
                const float4* b4 = reinterpret_cast<const float4*>(x + HW + base);
                const float4* c4 = reinterpret_cast<const float4*>(x + 2 * HW + base);
                float win[40];
#pragma unroll
                for (int q = 0; q < 10; ++q) {
                    const float4 a = a4[q], b = b4[q], c = c4[q];
                    win[4 * q + 0] = w0 * a.x + w1 * b.x + w2 * c.x;
                    win[4 * q + 1] = w0 * a.y + w1 * b.y + w2 * c.y;
                    win[4 * q + 2] = w0 * a.z + w1 * b.z + w2 * c.z;
                    win[4 * q + 3] = w0 * a.w + w1 * b.w + w2 * c.w;
                }
#pragma unroll
                for (int i = 0; i < PSZ; ++i) { re[i] = win[i]; im[i] = win[i + 8]; }
            } else {
                const int baseA = (phA * SCALE + r) * W + pwA * SCALE;
                const int baseB = (phB * SCALE + r) * W + pwB * SCALE;
#pragma unroll
                for (int i = 0; i < PSZ; ++i) {
                    re[i] = w0 * x[baseA + i] + w1 * x[HW + baseA + i] + w2 * x[2 * HW + baseA + i];
                    im[i] = w0 * x[baseB + i] + w1 * x[HW + baseB + i] + w2 * x[2 * HW + baseB + i];
                }
            }
        }

        fft32(re, im);   // FFT of rowA + i*rowB

        unsigned* cbA = cb + (2 * g) * 528;
        unsigned* cbB = cbA + 528;
        cbA[r] = pack_bf2(re[0], re[16]);
        cbB[r] = pack_bf2(im[0], im[16]);
#pragma unroll
        for (int k = 1; k <= 15; ++k) {
            const int m = 32 - k;
            const float far_ = 0.5f * (re[k] + re[m]);
            const float fai_ = 0.5f * (im[k] - im[m]);
            const float fbr_ = 0.5f * (im[k] + im[m]);
            const float fbi_ = 0.5f * (re[m] - re[k]);
            cbA[k * 33 + r] = pack_bf2(far_, fai_);
            cbB[k * 33 + r] = pack_bf2(fbr_, fbi_);
        }
    }

    __syncthreads();

    // ================= column stage =================
    {
        const int pl = lane >> 4, slot = lane & 15;
        const int p = blockIdx.x * 4 + pl;
        const unsigned* cbp = cb + pl * 528 + slot * 33;

        float cre[PSZ], cim[PSZ];
#pragma unroll
        for (int r2 = 0; r2 < PSZ; ++r2) {
            const unsigned u = cbp[r2];
            cre[r2] = bf_hi(u);
            cim[r2] = bf_lo(u);
        }

        fft32(cre, cim);

        float s0 = 0.0f, s1 = 0.0f;
        if (slot == 0) {
#pragma unroll
            for (int kr = 0; kr <= 16; ++kr) {
                const int m = (32 - kr) & 31;
                const float g0r = 0.5f * (cre[kr] + cre[m]);
                const float g0i = 0.5f * (cim[kr] - cim[m]);
                const float g1r = 0.5f * (cim[kr] + cim[m]);
                const float g1i = 0.5f * (cre[m] - cre[kr]);
                const float w0c = (kr >= 7 ? 1.0f : 0.0f) + ((kr >= 8 && kr <= 15) ? 1.0f : 0.0f);
                const float w16c = 1.0f + ((kr >= 1 && kr <= 15) ? 1.0f : 0.0f);
                if (w0c > 0.0f)
                    s0 = fmaf(w0c, __logf(g0r * g0r + g0i * g0i + 1.0f), s0);
                s1 = fmaf(w16c, __logf(g1r * g1r + g1i * g1i + 1.0f), s1);
            }
        } else {
            const float b1f = (slot >= 7) ? 1.0f : 0.0f;
            const float m1f = (slot >= 8) ? 1.0f : 0.0f;
#pragma unroll
            for (int kr = 0; kr < 32; ++kr) {
                const float lp = __logf(cre[kr] * cre[kr] + cim[kr] * cim[kr] + 1.0f);
                float wgt;
                if (kr >= 8 && kr <= 24)      wgt = 2.0f;
                else if (kr == 7)             wgt = 1.0f + m1f;
                else if (kr == 25)            wgt = b1f + 1.0f;
                else                          wgt = b1f + m1f;
                if (kr & 1) s1 = fmaf(wgt, lp, s1);
                else        s0 = fmaf(wgt, lp, s0);
            }
        }
        float s = s0 + s1;

#pragma unroll
        for (int off = 8; off >= 1; off >>= 1) s += __shfl_xor(s, off, 16);
        if (slot == 0 && p < total) out[p] = s;
    }
}

__global__ __launch_bounds__(1024) void max_kernel(
        const float* __restrict__ sums, int n, float* __restrict__ mx) {
    __shared__ float sm[16];
    float m = 0.0f;  // sums are >= 0
    for (int i = threadIdx.x; i < n; i += 1024) m = fmaxf(m, sums[i]);
#pragma unroll
    for (int off = 32; off >= 1; off >>= 1) m = fmaxf(m, __shfl_xor(m, off, 64));
    if ((threadIdx.x & 63) == 0) sm[threadIdx.x >> 6] = m;
    __syncthreads();
    if (threadIdx.x == 0) {
#pragma unroll
        for (int i = 1; i < 16; ++i) m = fmaxf(m, sm[i]);
        mx[0] = m;
    }
}

__global__ __launch_bounds__(256) void norm_kernel(
        float* __restrict__ out, int n, const float* __restrict__ mx) {
    const int i = blockIdx.x * 256 + threadIdx.x;
    if (i < n) out[i] = out[i] / mx[0];
}

extern "C" void kernel_launch(void* const* d_in, const int* in_sizes, int n_in,
                              void* d_out, int out_size, void* d_ws, size_t ws_size,
                              hipStream_t stream) {
    const float* x = (const float*)d_in[0];
    const float* w = (const float*)d_in[1];
    float* out = (float*)d_out;

    const int HWi = in_sizes[0] / 3;
    const int H = (int)(sqrt((double)HWi) + 0.5);
    const int W = H;
    const long long HW = (long long)H * W;
    const int mat = (int)(sqrt((double)out_size) + 0.5);
    const int total = mat * mat;
    const int blocksA = (total + 3) / 4;

    float* maxbuf = (float*)d_ws;
    float* gray = (float*)((char*)d_ws + 256);
    const size_t need = 256 + (size_t)HW * 4;

    if (ws_size >= need && (W & 3) == 0) {
        const int n4 = (int)(HW / 4);
        hipLaunchKernelGGL(gray_kernel, dim3((n4 + 255) / 256), dim3(256), 0, stream,
                           x, w, gray, n4, HW);
        hipLaunchKernelGGL((hfdft_patch_kernel<true>), dim3(blocksA), dim3(64), 0, stream,
                           gray, w, out, H, W, mat, mat);
    } else {
        hipLaunchKernelGGL((hfdft_patch_kernel<false>), dim3(blocksA), dim3(64), 0, stream,
                           x, w, out, H, W, mat, mat);
    }
    hipLaunchKernelGGL(max_kernel, dim3(1), dim3(1024), 0, stream, out, total, maxbuf);
    hipLaunchKernelGGL(norm_kernel, dim3((total + 255) / 256), dim3(256), 0, stream,
                       out, total, maxbuf);
}